// Round 14
// baseline (31.516 us; speedup 1.0000x reference)
//
#include <hip/hip_runtime.h>

#define HH 512
#define WW 512
#define NIMG 16
#define EPSF 1e-5f
#define INV81 (1.0f / 81.0f)

// lane l receives lane l-1's value; lane 0 -> 0  (wave_shr:1, bound_ctrl=1)
__device__ __forceinline__ float dpp_shr1(float x) {
    return __int_as_float(__builtin_amdgcn_update_dpp(
        0, __float_as_int(x), 0x138, 0xF, 0xF, true));
}
// lane l receives lane l+1's value; lane 63 -> 0  (wave_shl:1, bound_ctrl=1)
__device__ __forceinline__ float dpp_shl1(float x) {
    return __int_as_float(__builtin_amdgcn_update_dpp(
        0, __float_as_int(x), 0x130, 0xF, 0xF, true));
}

// Streaming warm kernel: pure read of all 33.5 MB, no dependent consumption
// (keep-alive via asm, rule #17). XCD-aligned: block b -> XCD b&7 reads that
// XCD's two images, warming its private 4MB L2 + the shared L3 at full
// stream rate (the poison fill proves ~6.5 TB/s is reachable in this state).
// 2048 blocks x 256 thr x 4 independent dwordx4 = exactly I+J once.
__global__ __launch_bounds__(256) void warm_l3(const float* __restrict__ Iin,
                                               const float* __restrict__ Jin) {
    const int tid = threadIdx.x;
    const int b   = blockIdx.x;
    const int xcd = b & 7;               // HW round-robin XCD of this block
    const int j   = b >> 3;              // 0..255 within XCD
    const float4* If = (const float4*)Iin;
    const float4* Jf = (const float4*)Jin;
    // image pair of this XCD: f4 offset xcd*131072, spans 2 images (1MB x2... wait: 2 imgs = 131072 f4)
    const size_t base = (size_t)xcd * 131072 + (size_t)j * 256 + (size_t)tid;
    float4 a0 = If[base];
    float4 a1 = If[base + 65536];
    float4 b0 = Jf[base];
    float4 b1 = Jf[base + 65536];
    float s = ((a0.x + a0.y) + (a0.z + a0.w)) + ((a1.x + a1.y) + (a1.z + a1.w))
            + ((b0.x + b0.y) + (b0.z + b0.w)) + ((b1.x + b1.y) + (b1.z + b1.w));
    asm volatile("" :: "v"(s));          // keep loads live, no DCE
}

// ncc_main: identical to R13 (verified correct, 29.2us cold).
__global__ __launch_bounds__(512, 4) void ncc_main(const float* __restrict__ Iin,
                                                   const float* __restrict__ Jin,
                                                   double* __restrict__ acc,
                                                   unsigned* __restrict__ cnt,
                                                   float* __restrict__ out) {
    __shared__ float4 ring4[16][2][128];  // 64 KB: [slot][img][A(0..63)|B(64..127)]
    __shared__ float wsum[8];

    const int tid  = threadIdx.x;
    const int lane = tid & 63;
    const int w    = tid >> 6;           // wave id 0..7
    const int xcd  = blockIdx.x & 7;
    const int idx  = blockIdx.x >> 3;    // 0..63 within XCD
    const int n    = (xcd << 1) | (idx >> 5);   // image
    const int y0   = (idx & 31) << 4;           // strip base output row
    const int c0   = lane << 3;          // 8 cols per lane (global addressing)

    const float* Ib = Iin + (size_t)n * (HH * WW);
    const float* Jb = Jin + (size_t)n * (HH * WW);

    auto gload = [&](int r, float4& a0, float4& a1, float4& b0, float4& b1) {
        if (r >= 0 && r < HH) {           // wave-uniform
            const float4* pI = (const float4*)(Ib + (size_t)r * WW + c0);
            const float4* pJ = (const float4*)(Jb + (size_t)r * WW + c0);
            a0 = pI[0]; a1 = pI[1]; b0 = pJ[0]; b1 = pJ[1];
        } else {
            a0 = a1 = b0 = b1 = make_float4(0.f, 0.f, 0.f, 0.f);
        }
    };
    auto swrite = [&](int r, const float4& a0, const float4& a1,
                             const float4& b0, const float4& b1) {
        const int sl = (r + 16) & 15;
        ring4[sl][0][lane]      = a0;     // A region: byte 16*lane
        ring4[sl][0][64 + lane] = a1;     // B region: byte 1024+16*lane
        ring4[sl][1][lane]      = b0;
        ring4[sl][1][64 + lane] = b1;
    };

    // Prologue: the 16 step-0 window rows (y0-4 .. y0+11), 2 per wave.
    {
        float4 p0, p1, q0, q1, r0, r1, s0, s1;
        gload(y0 - 4 + w, p0, p1, q0, q1);
        gload(y0 + 4 + w, r0, r1, s0, s1);
        swrite(y0 - 4 + w, p0, p1, q0, q1);
        swrite(y0 + 4 + w, r0, r1, s0, s1);
    }
    __syncthreads();                      // barrier 1

    // Step-1 rows issued here: latency hides under step-0 compute.
    float4 na0, na1, nb0, nb1;            // row y0+12+w
    gload(y0 + 12 + w, na0, na1, nb0, nb1);

    auto hbox = [&](const float (&C)[8], float (&B)[8]) {
        float H[16];
        #pragma unroll
        for (int k = 0; k < 4; ++k) H[k] = dpp_shr1(C[4 + k]);   // lane-1 cols
        #pragma unroll
        for (int k = 0; k < 8; ++k) H[4 + k] = C[k];
        #pragma unroll
        for (int k = 0; k < 4; ++k) H[12 + k] = dpp_shl1(C[k]);  // lane+1 cols
        float s = ((H[0] + H[1]) + (H[2] + H[3])) + ((H[4] + H[5]) + (H[6] + H[7])) + H[8];
        B[0] = s;
        #pragma unroll
        for (int i = 1; i < 8; ++i) { s += H[i + 8] - H[i - 1]; B[i] = s; }
    };

    float local = 0.f;

    auto dorow = [&](int R) {
        float SI[8], SJ[8], SI2[8], SJ2[8], SIJ[8];
        #pragma unroll
        for (int c = 0; c < 8; ++c) { SI[c]=0.f; SJ[c]=0.f; SI2[c]=0.f; SJ2[c]=0.f; SIJ[c]=0.f; }
        #pragma unroll
        for (int k = 0; k < 9; ++k) {
            const int sl = (R - 4 + k + 16) & 15;
            const float4 i0 = ring4[sl][0][lane];
            const float4 i1 = ring4[sl][0][64 + lane];
            const float4 j0 = ring4[sl][1][lane];
            const float4 j1 = ring4[sl][1][64 + lane];
            const float ai[8] = {i0.x, i0.y, i0.z, i0.w, i1.x, i1.y, i1.z, i1.w};
            const float bj[8] = {j0.x, j0.y, j0.z, j0.w, j1.x, j1.y, j1.z, j1.w};
            #pragma unroll
            for (int c = 0; c < 8; ++c) {
                SI[c] += ai[c];  SJ[c] += bj[c];
                SI2[c] = fmaf(ai[c], ai[c], SI2[c]);
                SJ2[c] = fmaf(bj[c], bj[c], SJ2[c]);
                SIJ[c] = fmaf(ai[c], bj[c], SIJ[c]);
            }
        }
        float BI[8], BJ[8], BI2[8], BJ2[8], BIJ[8];
        hbox(SI, BI); hbox(SJ, BJ); hbox(SI2, BI2); hbox(SJ2, BJ2); hbox(SIJ, BIJ);
        #pragma unroll
        for (int c = 0; c < 8; ++c) {
            const float tI = BI[c] * INV81;
            const float tJ = BJ[c] * INV81;
            const float cross = fmaf(-tI, BJ[c], BIJ[c]);
            const float Iv    = fmaf(-tI, BI[c], BI2[c]);
            const float Jv    = fmaf(-tJ, BJ[c], BJ2[c]);
            const float den   = fmaf(Iv, Jv, EPSF);
            local = fmaf(cross * cross, __builtin_amdgcn_rcpf(den), local);
        }
    };

    // Step 0: rows y0 .. y0+7 (windows y0-4 .. y0+11, all resident).
    dorow(y0 + w);
    __syncthreads();                      // barrier 2
    swrite(y0 + 12 + w, na0, na1, nb0, nb1);  // overwrite dead slots (-4..+3)
    __syncthreads();                      // barrier 3
    // Step 1: rows y0+8 .. y0+15 (windows y0+4 .. y0+19, all resident).
    dorow(y0 + 8 + w);

    // wave reduction, block reduction, one atomic per block; last block finalizes
    #pragma unroll
    for (int off = 32; off > 0; off >>= 1) local += __shfl_down(local, off);
    if (lane == 0) wsum[w] = local;
    __syncthreads();
    if (tid == 0) {
        float b = 0.f;
        #pragma unroll
        for (int k = 0; k < 8; ++k) b += wsum[k];
        atomicAdd(acc, (double)b);
        __threadfence();
        const unsigned old = atomicAdd(cnt, 1u);
        if (old == gridDim.x - 1) {
            const double t = atomicAdd(acc, 0.0);   // coherent read of final sum
            out[0] = 1.0f - (float)(t * (1.0 / (double)((size_t)NIMG * HH * WW)));
        }
    }
}

extern "C" void kernel_launch(void* const* d_in, const int* in_sizes, int n_in,
                              void* d_out, int out_size, void* d_ws, size_t ws_size,
                              hipStream_t stream) {
    const float* I = (const float*)d_in[0];
    const float* J = (const float*)d_in[1];
    float* out = (float*)d_out;
    double* acc = (double*)d_ws;
    unsigned* cnt = (unsigned*)((char*)d_ws + 8);

    hipMemsetAsync(d_ws, 0, 16, stream);
    // Pass 1: pure streaming warm of I+J into L2/L3 (XCD-aligned).
    warm_l3<<<2048, 256, 0, stream>>>(I, J);
    // Pass 2: compute with warm caches.
    ncc_main<<<512, 512, 0, stream>>>(I, J, acc, cnt, out);
}

// Round 15
// 15.929 us; speedup vs baseline: 1.9786x; 1.9786x over previous
//
#include <hip/hip_runtime.h>

#define HH 512
#define WW 512
#define NIMG 16
#define EPSF 1e-5f
#define INV81 (1.0f / 81.0f)

// lane l receives lane l-1's value; lane 0 -> 0  (wave_shr:1, bound_ctrl=1)
__device__ __forceinline__ float dpp_shr1(float x) {
    return __int_as_float(__builtin_amdgcn_update_dpp(
        0, __float_as_int(x), 0x138, 0xF, 0xF, true));
}
// lane l receives lane l+1's value; lane 63 -> 0  (wave_shl:1, bound_ctrl=1)
__device__ __forceinline__ float dpp_shl1(float x) {
    return __int_as_float(__builtin_amdgcn_update_dpp(
        0, __float_as_int(x), 0x130, 0xF, 0xF, true));
}

// Body identical to R13 (16-slot conflict-free LDS ring, DPP hbox, XCD
// swizzle). R15 change: NO same-address atomics anywhere. Each block
// plain-stores its partial sum to part[bid]; a 1-block final kernel
// reduces the 512 partials and writes d_out. Also removes the memset
// graph node (nothing needs zero-init) and the __threadfence.
__global__ __launch_bounds__(512, 4) void ncc_main(const float* __restrict__ Iin,
                                                   const float* __restrict__ Jin,
                                                   float* __restrict__ part) {
    __shared__ float4 ring4[16][2][128];  // 64 KB: [slot][img][A(0..63)|B(64..127)]
    __shared__ float wsum[8];

    const int tid  = threadIdx.x;
    const int lane = tid & 63;
    const int w    = tid >> 6;           // wave id 0..7
    const int xcd  = blockIdx.x & 7;
    const int idx  = blockIdx.x >> 3;    // 0..63 within XCD
    const int n    = (xcd << 1) | (idx >> 5);   // image
    const int y0   = (idx & 31) << 4;           // strip base output row
    const int c0   = lane << 3;          // 8 cols per lane (global addressing)

    const float* Ib = Iin + (size_t)n * (HH * WW);
    const float* Jb = Jin + (size_t)n * (HH * WW);

    auto gload = [&](int r, float4& a0, float4& a1, float4& b0, float4& b1) {
        if (r >= 0 && r < HH) {           // wave-uniform
            const float4* pI = (const float4*)(Ib + (size_t)r * WW + c0);
            const float4* pJ = (const float4*)(Jb + (size_t)r * WW + c0);
            a0 = pI[0]; a1 = pI[1]; b0 = pJ[0]; b1 = pJ[1];
        } else {
            a0 = a1 = b0 = b1 = make_float4(0.f, 0.f, 0.f, 0.f);
        }
    };
    auto swrite = [&](int r, const float4& a0, const float4& a1,
                             const float4& b0, const float4& b1) {
        const int sl = (r + 16) & 15;
        ring4[sl][0][lane]      = a0;     // A region: byte 16*lane
        ring4[sl][0][64 + lane] = a1;     // B region: byte 1024+16*lane
        ring4[sl][1][lane]      = b0;
        ring4[sl][1][64 + lane] = b1;
    };

    // Prologue: the 16 step-0 window rows (y0-4 .. y0+11), 2 per wave.
    {
        float4 p0, p1, q0, q1, r0, r1, s0, s1;
        gload(y0 - 4 + w, p0, p1, q0, q1);
        gload(y0 + 4 + w, r0, r1, s0, s1);
        swrite(y0 - 4 + w, p0, p1, q0, q1);
        swrite(y0 + 4 + w, r0, r1, s0, s1);
    }
    __syncthreads();                      // barrier 1

    // Step-1 rows issued here: latency hides under step-0 compute.
    float4 na0, na1, nb0, nb1;            // row y0+12+w
    gload(y0 + 12 + w, na0, na1, nb0, nb1);

    auto hbox = [&](const float (&C)[8], float (&B)[8]) {
        float H[16];
        #pragma unroll
        for (int k = 0; k < 4; ++k) H[k] = dpp_shr1(C[4 + k]);   // lane-1 cols
        #pragma unroll
        for (int k = 0; k < 8; ++k) H[4 + k] = C[k];
        #pragma unroll
        for (int k = 0; k < 4; ++k) H[12 + k] = dpp_shl1(C[k]);  // lane+1 cols
        float s = ((H[0] + H[1]) + (H[2] + H[3])) + ((H[4] + H[5]) + (H[6] + H[7])) + H[8];
        B[0] = s;
        #pragma unroll
        for (int i = 1; i < 8; ++i) { s += H[i + 8] - H[i - 1]; B[i] = s; }
    };

    float local = 0.f;

    auto dorow = [&](int R) {
        float SI[8], SJ[8], SI2[8], SJ2[8], SIJ[8];
        #pragma unroll
        for (int c = 0; c < 8; ++c) { SI[c]=0.f; SJ[c]=0.f; SI2[c]=0.f; SJ2[c]=0.f; SIJ[c]=0.f; }
        #pragma unroll
        for (int k = 0; k < 9; ++k) {
            const int sl = (R - 4 + k + 16) & 15;
            const float4 i0 = ring4[sl][0][lane];
            const float4 i1 = ring4[sl][0][64 + lane];
            const float4 j0 = ring4[sl][1][lane];
            const float4 j1 = ring4[sl][1][64 + lane];
            const float ai[8] = {i0.x, i0.y, i0.z, i0.w, i1.x, i1.y, i1.z, i1.w};
            const float bj[8] = {j0.x, j0.y, j0.z, j0.w, j1.x, j1.y, j1.z, j1.w};
            #pragma unroll
            for (int c = 0; c < 8; ++c) {
                SI[c] += ai[c];  SJ[c] += bj[c];
                SI2[c] = fmaf(ai[c], ai[c], SI2[c]);
                SJ2[c] = fmaf(bj[c], bj[c], SJ2[c]);
                SIJ[c] = fmaf(ai[c], bj[c], SIJ[c]);
            }
        }
        float BI[8], BJ[8], BI2[8], BJ2[8], BIJ[8];
        hbox(SI, BI); hbox(SJ, BJ); hbox(SI2, BI2); hbox(SJ2, BJ2); hbox(SIJ, BIJ);
        #pragma unroll
        for (int c = 0; c < 8; ++c) {
            const float tI = BI[c] * INV81;
            const float tJ = BJ[c] * INV81;
            const float cross = fmaf(-tI, BJ[c], BIJ[c]);
            const float Iv    = fmaf(-tI, BI[c], BI2[c]);
            const float Jv    = fmaf(-tJ, BJ[c], BJ2[c]);
            const float den   = fmaf(Iv, Jv, EPSF);
            local = fmaf(cross * cross, __builtin_amdgcn_rcpf(den), local);
        }
    };

    // Step 0: rows y0 .. y0+7 (windows y0-4 .. y0+11, all resident).
    dorow(y0 + w);
    __syncthreads();                      // barrier 2
    swrite(y0 + 12 + w, na0, na1, nb0, nb1);  // overwrite dead slots (-4..+3)
    __syncthreads();                      // barrier 3
    // Step 1: rows y0+8 .. y0+15 (windows y0+4 .. y0+19, all resident).
    dorow(y0 + 8 + w);

    // wave reduction -> block reduction -> ONE PLAIN STORE per block
    #pragma unroll
    for (int off = 32; off > 0; off >>= 1) local += __shfl_down(local, off);
    if (lane == 0) wsum[w] = local;
    __syncthreads();
    if (tid == 0) {
        float b = 0.f;
        #pragma unroll
        for (int k = 0; k < 8; ++k) b += wsum[k];
        part[blockIdx.x] = b;             // distinct address per block
    }
}

// 1 block, 512 threads: reduce the 512 partials, write the scalar output.
__global__ __launch_bounds__(512) void ncc_final(const float* __restrict__ part,
                                                 float* __restrict__ out) {
    __shared__ float s[8];
    const int tid  = threadIdx.x;
    const int lane = tid & 63;
    const int w    = tid >> 6;
    float v = part[tid];
    #pragma unroll
    for (int off = 32; off > 0; off >>= 1) v += __shfl_down(v, off);
    if (lane == 0) s[w] = v;
    __syncthreads();
    if (tid == 0) {
        float t = 0.f;
        #pragma unroll
        for (int k = 0; k < 8; ++k) t += s[k];
        out[0] = 1.0f - t * (1.0f / (float)((size_t)NIMG * HH * WW));
    }
}

extern "C" void kernel_launch(void* const* d_in, const int* in_sizes, int n_in,
                              void* d_out, int out_size, void* d_ws, size_t ws_size,
                              hipStream_t stream) {
    const float* I = (const float*)d_in[0];
    const float* J = (const float*)d_in[1];
    float* out  = (float*)d_out;
    float* part = (float*)d_ws;          // 512 floats, fully rewritten each call

    // No memset node: part[] is fully written before it is read.
    ncc_main<<<512, 512, 0, stream>>>(I, J, part);
    ncc_final<<<1, 512, 0, stream>>>(part, out);
}